// Round 6
// baseline (742.969 us; speedup 1.0000x reference)
//
#include <hip/hip_runtime.h>

#define NBOX   2000
#define NPAD   2048      // padded to pow2 for bitonic sort
#define NCLS   81
#define NSLOT  300       // PADDING
#define MROW4  15876     // 28*28*81/4 float4 per mask row
#define NW32   64        // u32 mask words per row (2048 bits)

// ---- scratch as device globals (fixed small size; avoids any dependence on
// ws_size — a too-small d_ws would segfault and kill the container). Every
// element read is written earlier in the same kernel_launch call. ----
__device__ float4             g_boxes[NBOX];
__device__ unsigned long long g_keys[NPAD];
__device__ unsigned int       g_order[NPAD];
__device__ float4             g_sboxes[NBOX];
__device__ unsigned int       g_mask[NBOX * NW32];
__device__ int                g_kept[NSLOT + 1];   // kept_rank[300], n_keep

// Kernel 1: per-proposal decode (argmax class only) + NMS sort key.
__global__ __launch_bounds__(256)
void k_prep(const float* __restrict__ metadata,
            const float* __restrict__ deltas,
            const float* __restrict__ proposals,
            const float* __restrict__ scores) {
  int i = blockIdx.x * blockDim.x + threadIdx.x;
  if (i >= NPAD) return;
  if (i >= NBOX) { g_keys[i] = ~0ull; return; }
  float H = metadata[0], W = metadata[1], scale = metadata[2];
  float px1 = proposals[i*4+0] / scale;
  float py1 = proposals[i*4+1] / scale;
  float px2 = proposals[i*4+2] / scale;
  float py2 = proposals[i*4+3] / scale;
  float a = px2 - px1, b = py2 - py1;
  float cx = px1 + 0.5f*a, cy = py1 + 0.5f*b;
  const float* srow = scores + (size_t)i*NCLS;
  float best = srow[0]; int bc = 0;      // argmax over ALL classes, first-max
  float ms = srow[1];                    // max over classes 1..80
  for (int c = 1; c < NCLS; ++c) {
    float s = srow[c];
    if (s > best) { best = s; bc = c; }
    ms = fmaxf(ms, s);
  }
  const float* drow = deltas + (size_t)i*(4*NCLS) + bc*4;
  float dx = drow[0], dy = drow[1], dw = drow[2], dh = drow[3];
  float pcx = dx*a + cx, pcy = dy*b + cy;
  float pw = expf(dw)*a, ph = expf(dh)*b;
  float x1 = pcx - 0.5f*pw, y1 = pcy - 0.5f*ph;
  float x2 = pcx + 0.5f*pw, y2 = pcy + 0.5f*ph;
  x1 = fminf(fmaxf(x1, 0.f), W - 1.f);
  y1 = fminf(fmaxf(y1, 0.f), H - 1.f);
  x2 = fminf(fmaxf(x2, 0.f), W - 1.f);
  y2 = fminf(fmaxf(y2, 0.f), H - 1.f);
  g_boxes[i] = make_float4(x1, y1, x2, y2);
  // stable argsort(-score): descending score, ties -> ascending index.
  // scores >= 0 so float bits are order-monotonic; ~bits flips to descending.
  unsigned int sb = __float_as_uint(ms);
  g_keys[i] = (((unsigned long long)(~sb)) << 32) | (unsigned int)i;
}

// Kernel 2: single-block bitonic sort of 2048 u64 keys; emits order[] and
// score-sorted boxes.
__global__ __launch_bounds__(1024)
void k_sort() {
  __shared__ unsigned long long s[NPAD];
  int t = threadIdx.x;                 // 1024 threads
  s[t] = g_keys[t];
  s[t + 1024] = g_keys[t + 1024];
  for (int k = 2; k <= NPAD; k <<= 1) {
    for (int j = k >> 1; j > 0; j >>= 1) {
      __syncthreads();
      for (int l = t; l < NPAD; l += 1024) {
        int p = l ^ j;
        if (p > l) {
          bool up = ((l & k) == 0);
          unsigned long long va = s[l], vb = s[p];
          if ((va > vb) == up) { s[l] = vb; s[p] = va; }
        }
      }
    }
  }
  __syncthreads();
  for (int l = t; l < NPAD; l += 1024) {
    unsigned int idx = (unsigned int)s[l];
    g_order[l] = idx;
    if (l < NBOX) g_sboxes[l] = g_boxes[idx];
  }
}

// Kernel 3: suppression bit-matrix in sorted order. ONE WAVE PER ROW r.
// Iteration jj: lanes read consecutive sb[jj*64+lane] (conflict-free LDS),
// ballot the suppress predicate -> u64 = mask words {2jj, 2jj+1}; each lane
// captures its own word, one coalesced store per row.
__global__ __launch_bounds__(256)
void k_iou() {
  __shared__ float4 sb[NPAD];
  int t = threadIdx.x;                 // 256 = 4 waves -> 4 rows/block
  for (int l = t; l < NPAD; l += 256)
    sb[l] = (l < NBOX) ? g_sboxes[l] : make_float4(0.f, 0.f, 0.f, 0.f);
  __syncthreads();
  int r = blockIdx.x * 4 + (t >> 6);   // wave-uniform row; grid exact 500*4
  int lane = t & 63;
  float4 br = sb[r];
  float aarea = fmaxf(br.z - br.x, 0.f) * fmaxf(br.w - br.y, 0.f);
  unsigned int myw = 0;
  #pragma unroll 8
  for (int jj = 0; jj < 32; ++jj) {
    int j = jj * 64 + lane;
    float4 bj = sb[j];
    float ix1 = fmaxf(br.x, bj.x), iy1 = fmaxf(br.y, bj.y);
    float ix2 = fminf(br.z, bj.z), iy2 = fminf(br.w, bj.w);
    float inter = fmaxf(ix2 - ix1, 0.f) * fmaxf(iy2 - iy1, 0.f);
    float barea = fmaxf(bj.z - bj.x, 0.f) * fmaxf(bj.w - bj.y, 0.f);
    float iou = inter / fmaxf(aarea + barea - inter, 1e-8f);
    bool sup = (j > r) && (j < NBOX) && (iou > 0.5f);
    unsigned long long m = __ballot(sup);
    if ((lane >> 1) == jj)
      myw = (lane & 1) ? (unsigned int)(m >> 32) : (unsigned int)m;
  }
  g_mask[r * NW32 + lane] = myw;
}

// Kernel 4: serial greedy scan (wave 0) + boxes/scores output (all 256).
// Early-break at 300 kept (reference drops slots >= 300).
__global__ __launch_bounds__(256)
void k_scan_out(const float* __restrict__ scores,
                float* __restrict__ out_boxes,
                float* __restrict__ out_scores) {
  __shared__ int s_kept[NSLOT];
  __shared__ int s_src[NSLOT];
  __shared__ int s_nk;
  int t = threadIdx.x;                 // 256
  if (t < 64) {
    int lane = t;
    unsigned int removed = 0;
    int k = 0;
    unsigned int r0 = g_mask[0*NW32 + lane];
    unsigned int r1 = g_mask[1*NW32 + lane];
    unsigned int r2 = g_mask[2*NW32 + lane];
    unsigned int r3 = g_mask[3*NW32 + lane];
    for (int i = 0; i < NBOX; ++i) {
      unsigned int wv = __shfl(removed, i >> 5);
      bool alive = ((wv >> (i & 31)) & 1u) == 0u;
      unsigned int row = r0;
      r0 = r1; r1 = r2; r2 = r3;
      int nf = i + 4;
      r3 = (nf < NBOX) ? g_mask[nf * NW32 + lane] : 0u;
      if (alive) {                     // wave-uniform branch
        removed |= row;
        if (lane == 0) s_kept[k] = i;
        ++k;
        if (k == NSLOT) break;
      }
    }
    if (lane == 0) s_nk = k;
  }
  __syncthreads();
  int nk = s_nk;
  if (t == 0) g_kept[NSLOT] = nk;
  for (int s2 = t; s2 < NSLOT; s2 += 256) {
    int rank = (s2 < nk) ? s_kept[s2] : 0;
    g_kept[s2] = rank;
    s_src[s2] = (s2 < nk) ? (int)g_order[rank] : 0;
  }
  __syncthreads();
  for (int idx = t; idx < NSLOT * 4; idx += 256) {
    int s2 = idx >> 2;
    const float* bp = (const float*)&g_boxes[s_src[s2]];
    out_boxes[idx] = (s2 < nk) ? bp[idx & 3] : 0.f;
  }
  for (int idx = t; idx < NSLOT * NCLS; idx += 256) {
    int s2 = idx / NCLS;
    int c  = idx - s2 * NCLS;
    out_scores[idx] = (s2 < nk) ? scores[(size_t)s_src[s2] * NCLS + c] : 0.f;
  }
}

// Kernel 5: masks_out (300 x 28*28*81), float4 copy rows.
__global__ __launch_bounds__(256)
void k_mask_out(const float4* __restrict__ masks,
                float4* __restrict__ out) {
  int s = blockIdx.y;
  int nk = g_kept[NSLOT];
  bool valid = s < nk;
  int src = valid ? (int)g_order[g_kept[s]] : 0;
  const float4* mrow = masks + (size_t)src * MROW4;
  float4* orow = out + (size_t)s * MROW4;
  int stride = gridDim.x * blockDim.x;
  for (int idx = blockIdx.x * blockDim.x + threadIdx.x; idx < MROW4; idx += stride) {
    orow[idx] = valid ? mrow[idx] : make_float4(0.f, 0.f, 0.f, 0.f);
  }
}

extern "C" void kernel_launch(void* const* d_in, const int* in_sizes, int n_in,
                              void* d_out, int out_size, void* d_ws, size_t ws_size,
                              hipStream_t stream) {
  const float* metadata  = (const float*)d_in[0];
  const float* deltas    = (const float*)d_in[1];
  const float* proposals = (const float*)d_in[2];
  const float* scores    = (const float*)d_in[3];
  const float4* masks    = (const float4*)d_in[4];   // 28*28*81 f32 per row, 16B aligned

  float* out_boxes  = (float*)d_out;                 // 300*4
  float* out_scores = out_boxes + NSLOT*4;           // 300*81
  float4* out_masks = (float4*)(out_scores + NSLOT*NCLS);  // byte off 102000, 16B aligned

  k_prep<<<NPAD/256, 256, 0, stream>>>(metadata, deltas, proposals, scores);
  k_sort<<<1, 1024, 0, stream>>>();
  k_iou<<<NBOX/4, 256, 0, stream>>>();
  k_scan_out<<<1, 256, 0, stream>>>(scores, out_boxes, out_scores);
  k_mask_out<<<dim3(63, NSLOT), 256, 0, stream>>>(masks, out_masks);
}